// Round 13
// baseline (903.810 us; speedup 1.0000x reference)
//
#include <hip/hip_runtime.h>

#define NPTS 262144
#define KVOL 27
#define NPAIRS 65536
#define TP (KVOL*NPAIRS)     // 1769472 pairs
#define CH 64
#define NT32 (NPTS/32)       // 8192 32-row output tiles
#define NSEG (NT32*32)       // 262144 segments (k padded to 32)
#define NBLK2 2048           // conv blocks (4 waves, each owns a 32-row tile)
#define MAXR 12              // max collision rounds per (seg,slot); P(exceed) ~ 0
#define SPILLMAX 131072      // spill capacity (entries)

typedef __attribute__((ext_vector_type(8))) short bf16x8;
typedef __attribute__((ext_vector_type(4))) float f32x4;

__device__ inline unsigned short f2bf(float x){
  unsigned int u = __float_as_uint(x);
  u += 0x7FFFu + ((u >> 16) & 1u);   // RNE
  return (unsigned short)(u >> 16);
}

__device__ inline bf16x8 pack8(float4 a, float4 b){
  bf16x8 r;
  r[0]=(short)f2bf(a.x); r[1]=(short)f2bf(a.y); r[2]=(short)f2bf(a.z); r[3]=(short)f2bf(a.w);
  r[4]=(short)f2bf(b.x); r[5]=(short)f2bf(b.y); r[6]=(short)f2bf(b.z); r[7]=(short)f2bf(b.w);
  return r;
}

// ---- fused: feat->bf16 (bf16 path), weight pack, count + DIRECT bin write ----
template<bool BF16G>
__global__ void k_pre2(const float* __restrict__ feat, const float* __restrict__ w,
                       const int2* __restrict__ km, unsigned short* __restrict__ featb,
                       unsigned short* __restrict__ wpack, int* __restrict__ cnt,
                       int* __restrict__ records, int2* __restrict__ spill,
                       int* __restrict__ spillcnt, int C){
  int i = blockIdx.x*256 + threadIdx.x;
  if (BF16G){
    float4 v = ((const float4*)feat)[i];     // grid sized to NPTS*CH/4
    ushort4 r;
    r.x = f2bf(v.x); r.y = f2bf(v.y); r.z = f2bf(v.z); r.w = f2bf(v.w);
    ((ushort4*)featb)[i] = r;
  }
  if (i < TP){
    int2 io = km[i];
    int k = i >> 16;
    int seg = ((io.y >> 5) << 5) | k;
    int rank = atomicAdd(&cnt[seg], 1);
    int rec = io.x | ((io.y & 31) << 18);
    if (rank < C) records[seg*C + rank] = rec;
    else {
      int sp = atomicAdd(spillcnt, 1);
      if (sp < SPILLMAX) spill[sp] = make_int2(seg, rec);
    }
  }
  if (i < KVOL*CH*CH){
    int j = i & 7, col = (i >> 3) & 63, kb = (i >> 9) & 7, k = i >> 12;
    wpack[i] = f2bf(w[(k*CH + kb*8 + j)*CH + col]);
  }
}

// ---- conv: wave owns 32 rows; binned records; LDS slot table; reg acc ----
template<bool BF16G>
__global__ __launch_bounds__(256, BF16G ? 8 : 4) void k_conv13(
    const unsigned short* __restrict__ featb, const float* __restrict__ featf,
    const unsigned short* __restrict__ wpack, const int* __restrict__ records,
    const int* __restrict__ cnt, const int2* __restrict__ spill,
    const int* __restrict__ spillcnt, int C,
    float* __restrict__ out, float* __restrict__ partials)
{
  __shared__ int lcnt[4][32];
  __shared__ int lslot[4][MAXR*32];
  __shared__ float sred[4][2][64];

  int tid = threadIdx.x;
  int wv = tid>>6, l = tid&63, lg = l>>4, li = l&15;
  int t32 = blockIdx.x*4 + wv;      // 32-row tile
  int segbase = t32 << 5;

  const bf16x8* fb = (const bf16x8*)featb;
  const float4* ff = (const float4*)featf;
  const bf16x8* wbase = ((const bf16x8*)wpack) + lg*64 + li;

  f32x4 acc[2][4];
  #pragma unroll
  for (int rt = 0; rt < 2; rt++)
    #pragma unroll
    for (int ct = 0; ct < 4; ct++) acc[rt][ct] = (f32x4)(0.0f);

  // all 27 segment counts in one lane-load
  int myc = (l < KVOL) ? cnt[segbase + l] : 0;

  int tot_cur = __builtin_amdgcn_readlane(myc, 0);
  int rec_pf = 0;
  if (l < min(tot_cur, C)) rec_pf = records[segbase*C + l];

  for (int k = 0; k < KVOL; k++){
    int tot = tot_cur;
    int tot_nx = (k < KVOL-1) ? __builtin_amdgcn_readlane(myc, k+1) : 0;
    int rec_nx = 0;
    if (l < min(tot_nx, C)) rec_nx = records[(segbase + k + 1)*C + l];

    if (tot > 0){
      // B fragments for offset k (L2-hot)
      bf16x8 B[4][2];
      #pragma unroll
      for (int ct = 0; ct < 4; ct++)
        #pragma unroll
        for (int h = 0; h < 2; h++)
          B[ct][h] = wbase[k*512 + h*256 + ct*16];

      // slot table from prefetched bin records
      if (l < 32) lcnt[wv][l] = 0;
      int bcnt = min(tot, C);
      if (l < bcnt){
        int slot = (rec_pf >> 18) & 31;
        int rank = atomicAdd(&lcnt[wv][slot], 1);
        if (rank < MAXR) lslot[wv][rank*32 + slot] = rec_pf;
      }
      int cnt0 = min(lcnt[wv][li], MAXR);
      int cnt1 = min(lcnt[wv][16 + li], MAXR);

      for (int r = 0; r < MAXR; r++){
        bool v0 = (r < cnt0), v1 = (r < cnt1);
        if (__ballot(v0 || v1) == 0ull) break;
        int rr0 = lslot[wv][r*32 + li];
        int rr1 = lslot[wv][r*32 + 16 + li];
        bf16x8 X00 = (bf16x8)(short)0, X01 = (bf16x8)(short)0;
        bf16x8 X10 = (bf16x8)(short)0, X11 = (bf16x8)(short)0;
        if (v0){
          int in = rr0 & 0x3FFFF;
          if (BF16G){ X00 = fb[in*8 + lg]; X01 = fb[in*8 + 4 + lg]; }
          else {
            float4 u0 = ff[in*16 + lg*2],     u1 = ff[in*16 + lg*2 + 1];
            float4 u2 = ff[in*16 + 8 + lg*2], u3 = ff[in*16 + 8 + lg*2 + 1];
            X00 = pack8(u0, u1); X01 = pack8(u2, u3);
          }
        }
        if (v1){
          int in = rr1 & 0x3FFFF;
          if (BF16G){ X10 = fb[in*8 + lg]; X11 = fb[in*8 + 4 + lg]; }
          else {
            float4 u0 = ff[in*16 + lg*2],     u1 = ff[in*16 + lg*2 + 1];
            float4 u2 = ff[in*16 + 8 + lg*2], u3 = ff[in*16 + 8 + lg*2 + 1];
            X10 = pack8(u0, u1); X11 = pack8(u2, u3);
          }
        }
        if (__ballot(v0)){
          #pragma unroll
          for (int ct = 0; ct < 4; ct++){
            acc[0][ct] = __builtin_amdgcn_mfma_f32_16x16x32_bf16(X00, B[ct][0], acc[0][ct], 0, 0, 0);
            acc[0][ct] = __builtin_amdgcn_mfma_f32_16x16x32_bf16(X01, B[ct][1], acc[0][ct], 0, 0, 0);
          }
        }
        if (__ballot(v1)){
          #pragma unroll
          for (int ct = 0; ct < 4; ct++){
            acc[1][ct] = __builtin_amdgcn_mfma_f32_16x16x32_bf16(X10, B[ct][0], acc[1][ct], 0, 0, 0);
            acc[1][ct] = __builtin_amdgcn_mfma_f32_16x16x32_bf16(X11, B[ct][1], acc[1][ct], 0, 0, 0);
          }
        }
      }
    }
    rec_pf = rec_nx; tot_cur = tot_nx;
  }

  // ---- spill pairs (rank >= C in k_pre2): correct, ~never hot ----
  int nsp = min(spillcnt[0], SPILLMAX);
  for (int s0 = 0; s0 < nsp; s0 += 64){
    int idx = s0 + l;
    int2 e = make_int2(-1, 0);
    if (idx < nsp) e = spill[idx];
    unsigned long long m = __ballot((e.x >= 0) && ((e.x >> 5) == t32));
    while (m){
      int j = __ffsll((long long)m) - 1; m &= m - 1;
      int sj = __shfl(e.x, j, 64);
      int rj = __shfl(e.y, j, 64);
      int kk = sj & 31;
      int slot = (rj >> 18) & 31, hh = slot >> 4, sl = slot & 15;
      bf16x8 Bs[4][2];
      #pragma unroll
      for (int ct = 0; ct < 4; ct++)
        #pragma unroll
        for (int h = 0; h < 2; h++)
          Bs[ct][h] = wbase[kk*512 + h*256 + ct*16];
      bool v = (li == sl);
      bf16x8 X0 = (bf16x8)(short)0, X1 = (bf16x8)(short)0;
      if (v){
        int in = rj & 0x3FFFF;
        if (BF16G){ X0 = fb[in*8 + lg]; X1 = fb[in*8 + 4 + lg]; }
        else {
          float4 u0 = ff[in*16 + lg*2],     u1 = ff[in*16 + lg*2 + 1];
          float4 u2 = ff[in*16 + 8 + lg*2], u3 = ff[in*16 + 8 + lg*2 + 1];
          X0 = pack8(u0, u1); X1 = pack8(u2, u3);
        }
      }
      if (hh == 0){
        #pragma unroll
        for (int ct = 0; ct < 4; ct++){
          acc[0][ct] = __builtin_amdgcn_mfma_f32_16x16x32_bf16(X0, Bs[ct][0], acc[0][ct], 0, 0, 0);
          acc[0][ct] = __builtin_amdgcn_mfma_f32_16x16x32_bf16(X1, Bs[ct][1], acc[0][ct], 0, 0, 0);
        }
      } else {
        #pragma unroll
        for (int ct = 0; ct < 4; ct++){
          acc[1][ct] = __builtin_amdgcn_mfma_f32_16x16x32_bf16(X0, Bs[ct][0], acc[1][ct], 0, 0, 0);
          acc[1][ct] = __builtin_amdgcn_mfma_f32_16x16x32_bf16(X1, Bs[ct][1], acc[1][ct], 0, 0, 0);
        }
      }
    }
  }

  // flush 32x64 rows from registers
  #pragma unroll
  for (int rt = 0; rt < 2; rt++)
    #pragma unroll
    for (int r = 0; r < 4; r++){
      int row = t32*32 + rt*16 + lg*4 + r;
      #pragma unroll
      for (int ct = 0; ct < 4; ct++)
        out[row*CH + ct*16 + li] = acc[rt][ct][r];
    }

  // BN stats partials
  float s1[4], s2[4];
  #pragma unroll
  for (int ct = 0; ct < 4; ct++){
    float a1 = 0.f, a2 = 0.f;
    #pragma unroll
    for (int rt = 0; rt < 2; rt++)
      #pragma unroll
      for (int r = 0; r < 4; r++){
        float v = acc[rt][ct][r];
        a1 += v; a2 += v*v;
      }
    a1 += __shfl_xor(a1, 16, 64); a1 += __shfl_xor(a1, 32, 64);
    a2 += __shfl_xor(a2, 16, 64); a2 += __shfl_xor(a2, 32, 64);
    s1[ct] = a1; s2[ct] = a2;
  }
  __syncthreads();
  if (l < 16){
    #pragma unroll
    for (int ct = 0; ct < 4; ct++){
      sred[wv][0][ct*16 + li] = s1[ct];
      sred[wv][1][ct*16 + li] = s2[ct];
    }
  }
  __syncthreads();
  if (tid < 128){
    int h = tid >> 6, c = tid & 63;
    float p = sred[0][h][c] + sred[1][h][c] + sred[2][h][c] + sred[3][h][c];
    partials[blockIdx.x*128 + tid] = p;
  }
}

// ---- parallel final stats reduce ----
__global__ void k_statred(const float* __restrict__ partials, float* __restrict__ stats){
  __shared__ float sm_[256];
  int c = blockIdx.x;       // 0..127
  int t = threadIdx.x;      // 256
  float s = 0.f;
  for (int b = t; b < NBLK2; b += 256) s += partials[b*128 + c];
  sm_[t] = s;
  __syncthreads();
  for (int d = 128; d > 0; d >>= 1){
    if (t < d) sm_[t] += sm_[t+d];
    __syncthreads();
  }
  if (t == 0) stats[c] = sm_[0];
}

// ---- BN (batch stats, biased var) + ReLU, in place ----
__global__ void k_bn(float* __restrict__ out, const float* __restrict__ stats,
                     const float* __restrict__ g, const float* __restrict__ b){
  int i = blockIdx.x * blockDim.x + threadIdx.x;  // NPTS*CH/4
  float4 v = ((const float4*)out)[i];
  int c0 = (i * 4) & 63;
  float vals[4] = {v.x, v.y, v.z, v.w};
  float res[4];
  #pragma unroll
  for (int q = 0; q < 4; q++){
    int c = c0 + q;
    float mean = stats[c] * (1.0f/NPTS);
    float var  = stats[64+c] * (1.0f/NPTS) - mean*mean;
    float inv  = rsqrtf(var + 1e-5f);
    float y = (vals[q] - mean) * inv * g[c] + b[c];
    res[q] = fmaxf(y, 0.0f);
  }
  float4 r; r.x=res[0]; r.y=res[1]; r.z=res[2]; r.w=res[3];
  ((float4*)out)[i] = r;
}

extern "C" void kernel_launch(void* const* d_in, const int* in_sizes, int n_in,
                              void* d_out, int out_size, void* d_ws, size_t ws_size,
                              hipStream_t stream) {
  const float* feat   = (const float*)d_in[0];
  const int*   kmap   = (const int*)d_in[3];
  const float* weight = (const float*)d_in[4];
  const float* bnw    = (const float*)d_in[5];
  const float* bnb    = (const float*)d_in[6];
  float* out = (float*)d_out;

  char* ws = (char*)d_ws;
  size_t cur = 0;
  auto take = [&](size_t bytes){
    cur = (cur + 255) & ~(size_t)255;
    size_t p = cur; cur += bytes; return p;
  };
  float* stats          = (float*)(ws + take(2*CH*sizeof(float)));
  float* partials       = (float*)(ws + take((size_t)NBLK2*128*sizeof(float)));
  int* cnt              = (int*)(ws + take((size_t)(NSEG+64)*4));   // + spillcnt at [NSEG]
  int2* spill           = (int2*)(ws + take((size_t)SPILLMAX*8));
  unsigned short* wpack = (unsigned short*)(ws + take((size_t)KVOL*CH*CH*2));
  size_t base = cur;
  // choose bin capacity C from remaining workspace (featb needed for bf16 path)
  size_t featb_bytes = (size_t)NPTS*CH*2;
  int C = 16;
  bool useBf16 = false;
  {
    size_t avail = (ws_size > base + featb_bytes + 512) ? (ws_size - base - featb_bytes - 512) : 0;
    size_t cmax = avail / ((size_t)NSEG*4);
    if (cmax >= 11){ useBf16 = true; C = (int)((cmax < 16) ? cmax : 16); }
  }
  int* records          = (int*)(ws + take((size_t)NSEG*(useBf16 ? C : 16)*4));
  if (!useBf16) C = 16;
  unsigned short* featb = (unsigned short*)(ws + take(featb_bytes));
  int* spillcnt = cnt + NSEG;

  hipMemsetAsync(cnt, 0, (size_t)(NSEG+64)*4, stream);

  const int2* km = (const int2*)kmap;
  if (useBf16)
    k_pre2<true><<<NPTS*CH/4/256, 256, 0, stream>>>(feat, weight, km, featb, wpack, cnt,
                                                    records, spill, spillcnt, C);
  else
    k_pre2<false><<<TP/256, 256, 0, stream>>>(feat, weight, km, featb, wpack, cnt,
                                              records, spill, spillcnt, C);

  if (useBf16)
    k_conv13<true><<<NBLK2, 256, 0, stream>>>(featb, feat, wpack, records, cnt, spill,
                                              spillcnt, C, out, partials);
  else
    k_conv13<false><<<NBLK2, 256, 0, stream>>>(featb, feat, wpack, records, cnt, spill,
                                               spillcnt, C, out, partials);

  k_statred<<<128, 256, 0, stream>>>(partials, stats);
  k_bn<<<NPTS*CH/4/256, 256, 0, stream>>>(out, stats, bnw, bnb);
}

// Round 14
// 741.524 us; speedup vs baseline: 1.2189x; 1.2189x over previous
//
#include <hip/hip_runtime.h>

#define NPTS 262144
#define KVOL 27
#define NPAIRS 65536
#define TP (KVOL*NPAIRS)     // 1769472 pairs
#define CH 64
#define NT32 (NPTS/32)       // 8192 32-row output tiles
#define NSEG (NT32*32)       // 262144 segments (k padded to 32)
#define NBLK2 2048           // conv blocks (4 waves, each owns a 32-row tile)
#define MAXR 12              // rounds cap (table path)
#define SPILLMAX 131072      // spill capacity (entries)

typedef __attribute__((ext_vector_type(8))) short bf16x8;
typedef __attribute__((ext_vector_type(4))) float f32x4;

__device__ inline unsigned short f2bf(float x){
  unsigned int u = __float_as_uint(x);
  u += 0x7FFFu + ((u >> 16) & 1u);   // RNE
  return (unsigned short)(u >> 16);
}

__device__ inline bf16x8 pack8(float4 a, float4 b){
  bf16x8 r;
  r[0]=(short)f2bf(a.x); r[1]=(short)f2bf(a.y); r[2]=(short)f2bf(a.z); r[3]=(short)f2bf(a.w);
  r[4]=(short)f2bf(b.x); r[5]=(short)f2bf(b.y); r[6]=(short)f2bf(b.z); r[7]=(short)f2bf(b.w);
  return r;
}

// ---- fused: feat->bf16 (bf16 path), weight pack, count + DIRECT bin write ----
template<bool BF16G>
__global__ void k_pre2(const float* __restrict__ feat, const float* __restrict__ w,
                       const int2* __restrict__ km, unsigned short* __restrict__ featb,
                       unsigned short* __restrict__ wpack, int* __restrict__ cnt,
                       int* __restrict__ records, int2* __restrict__ spill,
                       int* __restrict__ spillcnt, int C){
  int i = blockIdx.x*256 + threadIdx.x;
  if (BF16G){
    float4 v = ((const float4*)feat)[i];     // grid sized to NPTS*CH/4
    ushort4 r;
    r.x = f2bf(v.x); r.y = f2bf(v.y); r.z = f2bf(v.z); r.w = f2bf(v.w);
    ((ushort4*)featb)[i] = r;
  }
  if (i < TP){
    int2 io = km[i];
    int k = i >> 16;
    int seg = ((io.y >> 5) << 5) | k;
    int rank = atomicAdd(&cnt[seg], 1);
    int rec = io.x | ((io.y & 31) << 18);
    if (rank < C) records[seg*C + rank] = rec;
    else {
      int sp = atomicAdd(spillcnt, 1);
      if (sp < SPILLMAX) spill[sp] = make_int2(seg, rec);
    }
  }
  if (i < KVOL*CH*CH){
    int j = i & 7, col = (i >> 3) & 63, kb = (i >> 9) & 7, k = i >> 12;
    wpack[i] = f2bf(w[(k*CH + kb*8 + j)*CH + col]);
  }
}

// ---- sort each segment's bin by slot, pack per-slot counts into record bits ----
// out record format: in:18 | c_lo(slot p):5 @18 | c_hi(slot p+16):5 @23  (position p)
__global__ __launch_bounds__(256) void k_sort(const int* __restrict__ cnt,
                                              int* __restrict__ records,
                                              int2* __restrict__ spill,
                                              int* __restrict__ spillcnt){
  __shared__ int lcnt[4][32];
  __shared__ int lsl[4][15*32];
  __shared__ int tmp[4][16];
  int tid = threadIdx.x, wv = tid>>6, l = tid&63;
  int wave = blockIdx.x*4 + wv;
  for (int s = 0; s < 8; s++){
    int seg = wave*8 + s;
    int tot = cnt[seg];
    int bcnt = min(tot, 16);
    int raw = (l < bcnt) ? records[seg*16 + l] : 0;
    if (l < 32) lcnt[wv][l] = 0;
    if (l < 16) tmp[wv][l] = 0;
    __builtin_amdgcn_wave_barrier();
    if (l < bcnt){
      int sl = (raw >> 18) & 31;
      int rk = atomicAdd(&lcnt[wv][sl], 1);
      if (rk < 15) lsl[wv][rk*32 + sl] = raw & 0x3FFFF;
      else { int sp = atomicAdd(spillcnt, 1); if (sp < SPILLMAX) spill[sp] = make_int2(seg, raw); }
    }
    int c = (l < 32) ? min(lcnt[wv][l], 15) : 0;
    int p = c;
    #pragma unroll
    for (int d = 1; d < 32; d <<= 1){ int t = __shfl_up(p, d, 32); if ((l & 31) >= d) p += t; }
    int pfx = p - c;
    if (l < 32){
      for (int r = 0; r < c; r++) tmp[wv][pfx + r] = lsl[wv][r*32 + l];
    }
    __builtin_amdgcn_wave_barrier();
    if (l < 16){
      int c_lo = min(lcnt[wv][l], 15);
      int c_hi = min(lcnt[wv][l + 16], 15);
      records[seg*16 + l] = tmp[wv][l] | (c_lo << 18) | (c_hi << 23);
    }
  }
}

// ---- conv (sorted path): no LDS table; shfl-routed operands; 6 waves/EU ----
__global__ __launch_bounds__(256, 6) void k_conv14(
    const unsigned short* __restrict__ featb, const unsigned short* __restrict__ wpack,
    const int* __restrict__ records, const int2* __restrict__ spill,
    const int* __restrict__ spillcnt, float* __restrict__ out, float* __restrict__ partials)
{
  __shared__ float sred[4][2][64];
  int tid = threadIdx.x;
  int wv = tid>>6, l = tid&63, lg = l>>4, li = l&15;
  int t32 = blockIdx.x*4 + wv;
  int segbase = t32 << 5;

  const bf16x8* fb = (const bf16x8*)featb;
  const bf16x8* wbase = ((const bf16x8*)wpack) + lg*64 + li;

  f32x4 acc[2][4];
  #pragma unroll
  for (int rt = 0; rt < 2; rt++)
    #pragma unroll
    for (int ct = 0; ct < 4; ct++) acc[rt][ct] = (f32x4)(0.0f);

  int rec_pf = (l < 16) ? records[segbase*16 + l] : 0;

  for (int k = 0; k < KVOL; k++){
    int rec_nx = (k < KVOL-1 && l < 16) ? records[(segbase + k + 1)*16 + l] : 0;

    int cw = __shfl(rec_pf, li, 64);       // position-li word (counts carrier)
    int c_lo = (cw >> 18) & 31;
    int c_hi = (cw >> 23) & 31;
    int plo = c_lo;
    #pragma unroll
    for (int d = 1; d < 16; d <<= 1){ int t = __shfl_up(plo, d, 16); if (li >= d) plo += t; }
    int pfx_lo = plo - c_lo;
    int tot_lo = __shfl(plo, 15, 16);
    int phi = c_hi;
    #pragma unroll
    for (int d = 1; d < 16; d <<= 1){ int t = __shfl_up(phi, d, 16); if (li >= d) phi += t; }
    int pfx_hi = tot_lo + phi - c_hi;
    int nr = max(c_lo, c_hi);
    #pragma unroll
    for (int d = 1; d < 16; d <<= 1) nr = max(nr, __shfl_xor(nr, d, 16));

    if (nr > 0){
      bf16x8 B[4][2];
      #pragma unroll
      for (int ct = 0; ct < 4; ct++)
        #pragma unroll
        for (int h = 0; h < 2; h++)
          B[ct][h] = wbase[k*512 + h*256 + ct*16];

      for (int r = 0; r < nr; r++){
        int rec0 = __shfl(rec_pf, pfx_lo + r, 64);
        int rec1 = __shfl(rec_pf, pfx_hi + r, 64);
        bool v0 = (r < c_lo), v1 = (r < c_hi);
        bf16x8 X00 = (bf16x8)(short)0, X01 = (bf16x8)(short)0;
        bf16x8 X10 = (bf16x8)(short)0, X11 = (bf16x8)(short)0;
        if (v0){ int in = rec0 & 0x3FFFF; X00 = fb[in*8 + lg]; X01 = fb[in*8 + 4 + lg]; }
        if (v1){ int in = rec1 & 0x3FFFF; X10 = fb[in*8 + lg]; X11 = fb[in*8 + 4 + lg]; }
        if (__ballot(v0)){
          #pragma unroll
          for (int ct = 0; ct < 4; ct++){
            acc[0][ct] = __builtin_amdgcn_mfma_f32_16x16x32_bf16(X00, B[ct][0], acc[0][ct], 0, 0, 0);
            acc[0][ct] = __builtin_amdgcn_mfma_f32_16x16x32_bf16(X01, B[ct][1], acc[0][ct], 0, 0, 0);
          }
        }
        if (__ballot(v1)){
          #pragma unroll
          for (int ct = 0; ct < 4; ct++){
            acc[1][ct] = __builtin_amdgcn_mfma_f32_16x16x32_bf16(X10, B[ct][0], acc[1][ct], 0, 0, 0);
            acc[1][ct] = __builtin_amdgcn_mfma_f32_16x16x32_bf16(X11, B[ct][1], acc[1][ct], 0, 0, 0);
          }
        }
      }
    }
    rec_pf = rec_nx;
  }

  // ---- spill pairs (rare) ----
  int nsp = min(spillcnt[0], SPILLMAX);
  for (int s0 = 0; s0 < nsp; s0 += 64){
    int idx = s0 + l;
    int2 e = make_int2(-1, 0);
    if (idx < nsp) e = spill[idx];
    unsigned long long m = __ballot((e.x >= 0) && ((e.x >> 5) == t32));
    while (m){
      int j = __ffsll((long long)m) - 1; m &= m - 1;
      int sj = __shfl(e.x, j, 64);
      int rj = __shfl(e.y, j, 64);
      int kk = sj & 31;
      int slot = (rj >> 18) & 31, hh = slot >> 4, sl = slot & 15;
      bf16x8 Bs[4][2];
      #pragma unroll
      for (int ct = 0; ct < 4; ct++)
        #pragma unroll
        for (int h = 0; h < 2; h++)
          Bs[ct][h] = wbase[kk*512 + h*256 + ct*16];
      bool v = (li == sl);
      bf16x8 X0 = (bf16x8)(short)0, X1 = (bf16x8)(short)0;
      if (v){ int in = rj & 0x3FFFF; X0 = fb[in*8 + lg]; X1 = fb[in*8 + 4 + lg]; }
      if (hh == 0){
        #pragma unroll
        for (int ct = 0; ct < 4; ct++){
          acc[0][ct] = __builtin_amdgcn_mfma_f32_16x16x32_bf16(X0, Bs[ct][0], acc[0][ct], 0, 0, 0);
          acc[0][ct] = __builtin_amdgcn_mfma_f32_16x16x32_bf16(X1, Bs[ct][1], acc[0][ct], 0, 0, 0);
        }
      } else {
        #pragma unroll
        for (int ct = 0; ct < 4; ct++){
          acc[1][ct] = __builtin_amdgcn_mfma_f32_16x16x32_bf16(X0, Bs[ct][0], acc[1][ct], 0, 0, 0);
          acc[1][ct] = __builtin_amdgcn_mfma_f32_16x16x32_bf16(X1, Bs[ct][1], acc[1][ct], 0, 0, 0);
        }
      }
    }
  }

  // flush 32x64 rows
  #pragma unroll
  for (int rt = 0; rt < 2; rt++)
    #pragma unroll
    for (int r = 0; r < 4; r++){
      int row = t32*32 + rt*16 + lg*4 + r;
      #pragma unroll
      for (int ct = 0; ct < 4; ct++)
        out[row*CH + ct*16 + li] = acc[rt][ct][r];
    }

  // BN stats partials
  float s1[4], s2[4];
  #pragma unroll
  for (int ct = 0; ct < 4; ct++){
    float a1 = 0.f, a2 = 0.f;
    #pragma unroll
    for (int rt = 0; rt < 2; rt++)
      #pragma unroll
      for (int r = 0; r < 4; r++){
        float v = acc[rt][ct][r];
        a1 += v; a2 += v*v;
      }
    a1 += __shfl_xor(a1, 16, 64); a1 += __shfl_xor(a1, 32, 64);
    a2 += __shfl_xor(a2, 16, 64); a2 += __shfl_xor(a2, 32, 64);
    s1[ct] = a1; s2[ct] = a2;
  }
  __syncthreads();
  if (l < 16){
    #pragma unroll
    for (int ct = 0; ct < 4; ct++){
      sred[wv][0][ct*16 + li] = s1[ct];
      sred[wv][1][ct*16 + li] = s2[ct];
    }
  }
  __syncthreads();
  if (tid < 128){
    int h = tid >> 6, c = tid & 63;
    float p = sred[0][h][c] + sred[1][h][c] + sred[2][h][c] + sred[3][h][c];
    partials[blockIdx.x*128 + tid] = p;
  }
}

// ---- conv (fallback, R12-proven table path) ----
template<bool BF16G>
__global__ __launch_bounds__(256, 4) void k_conv13(
    const unsigned short* __restrict__ featb, const float* __restrict__ featf,
    const unsigned short* __restrict__ wpack, const int* __restrict__ records,
    const int* __restrict__ cnt, const int2* __restrict__ spill,
    const int* __restrict__ spillcnt, int C,
    float* __restrict__ out, float* __restrict__ partials)
{
  __shared__ int lcnt[4][32];
  __shared__ int lslot[4][MAXR*32];
  __shared__ float sred[4][2][64];

  int tid = threadIdx.x;
  int wv = tid>>6, l = tid&63, lg = l>>4, li = l&15;
  int t32 = blockIdx.x*4 + wv;
  int segbase = t32 << 5;

  const bf16x8* fb = (const bf16x8*)featb;
  const float4* ff = (const float4*)featf;
  const bf16x8* wbase = ((const bf16x8*)wpack) + lg*64 + li;

  f32x4 acc[2][4];
  #pragma unroll
  for (int rt = 0; rt < 2; rt++)
    #pragma unroll
    for (int ct = 0; ct < 4; ct++) acc[rt][ct] = (f32x4)(0.0f);

  int myc = (l < KVOL) ? cnt[segbase + l] : 0;
  int tot_cur = __builtin_amdgcn_readlane(myc, 0);
  int rec_pf = 0;
  if (l < min(tot_cur, C)) rec_pf = records[segbase*C + l];

  for (int k = 0; k < KVOL; k++){
    int tot = tot_cur;
    int tot_nx = (k < KVOL-1) ? __builtin_amdgcn_readlane(myc, k+1) : 0;
    int rec_nx = 0;
    if (l < min(tot_nx, C)) rec_nx = records[(segbase + k + 1)*C + l];

    if (tot > 0){
      bf16x8 B[4][2];
      #pragma unroll
      for (int ct = 0; ct < 4; ct++)
        #pragma unroll
        for (int h = 0; h < 2; h++)
          B[ct][h] = wbase[k*512 + h*256 + ct*16];

      if (l < 32) lcnt[wv][l] = 0;
      int bcnt = min(tot, C);
      if (l < bcnt){
        int slot = (rec_pf >> 18) & 31;
        int rank = atomicAdd(&lcnt[wv][slot], 1);
        if (rank < MAXR) lslot[wv][rank*32 + slot] = rec_pf;
      }
      int cnt0 = min(lcnt[wv][li], MAXR);
      int cnt1 = min(lcnt[wv][16 + li], MAXR);

      for (int r = 0; r < MAXR; r++){
        bool v0 = (r < cnt0), v1 = (r < cnt1);
        if (__ballot(v0 || v1) == 0ull) break;
        int rr0 = lslot[wv][r*32 + li];
        int rr1 = lslot[wv][r*32 + 16 + li];
        bf16x8 X00 = (bf16x8)(short)0, X01 = (bf16x8)(short)0;
        bf16x8 X10 = (bf16x8)(short)0, X11 = (bf16x8)(short)0;
        if (v0){
          int in = rr0 & 0x3FFFF;
          if (BF16G){ X00 = fb[in*8 + lg]; X01 = fb[in*8 + 4 + lg]; }
          else {
            float4 u0 = ff[in*16 + lg*2],     u1 = ff[in*16 + lg*2 + 1];
            float4 u2 = ff[in*16 + 8 + lg*2], u3 = ff[in*16 + 8 + lg*2 + 1];
            X00 = pack8(u0, u1); X01 = pack8(u2, u3);
          }
        }
        if (v1){
          int in = rr1 & 0x3FFFF;
          if (BF16G){ X10 = fb[in*8 + lg]; X11 = fb[in*8 + 4 + lg]; }
          else {
            float4 u0 = ff[in*16 + lg*2],     u1 = ff[in*16 + lg*2 + 1];
            float4 u2 = ff[in*16 + 8 + lg*2], u3 = ff[in*16 + 8 + lg*2 + 1];
            X10 = pack8(u0, u1); X11 = pack8(u2, u3);
          }
        }
        if (__ballot(v0)){
          #pragma unroll
          for (int ct = 0; ct < 4; ct++){
            acc[0][ct] = __builtin_amdgcn_mfma_f32_16x16x32_bf16(X00, B[ct][0], acc[0][ct], 0, 0, 0);
            acc[0][ct] = __builtin_amdgcn_mfma_f32_16x16x32_bf16(X01, B[ct][1], acc[0][ct], 0, 0, 0);
          }
        }
        if (__ballot(v1)){
          #pragma unroll
          for (int ct = 0; ct < 4; ct++){
            acc[1][ct] = __builtin_amdgcn_mfma_f32_16x16x32_bf16(X10, B[ct][0], acc[1][ct], 0, 0, 0);
            acc[1][ct] = __builtin_amdgcn_mfma_f32_16x16x32_bf16(X11, B[ct][1], acc[1][ct], 0, 0, 0);
          }
        }
      }
    }
    rec_pf = rec_nx; tot_cur = tot_nx;
  }

  int nsp = min(spillcnt[0], SPILLMAX);
  for (int s0 = 0; s0 < nsp; s0 += 64){
    int idx = s0 + l;
    int2 e = make_int2(-1, 0);
    if (idx < nsp) e = spill[idx];
    unsigned long long m = __ballot((e.x >= 0) && ((e.x >> 5) == t32));
    while (m){
      int j = __ffsll((long long)m) - 1; m &= m - 1;
      int sj = __shfl(e.x, j, 64);
      int rj = __shfl(e.y, j, 64);
      int kk = sj & 31;
      int slot = (rj >> 18) & 31, hh = slot >> 4, sl = slot & 15;
      bf16x8 Bs[4][2];
      #pragma unroll
      for (int ct = 0; ct < 4; ct++)
        #pragma unroll
        for (int h = 0; h < 2; h++)
          Bs[ct][h] = wbase[kk*512 + h*256 + ct*16];
      bool v = (li == sl);
      bf16x8 X0 = (bf16x8)(short)0, X1 = (bf16x8)(short)0;
      if (v){
        int in = rj & 0x3FFFF;
        if (BF16G){ X0 = fb[in*8 + lg]; X1 = fb[in*8 + 4 + lg]; }
        else {
          float4 u0 = ff[in*16 + lg*2],     u1 = ff[in*16 + lg*2 + 1];
          float4 u2 = ff[in*16 + 8 + lg*2], u3 = ff[in*16 + 8 + lg*2 + 1];
          X0 = pack8(u0, u1); X1 = pack8(u2, u3);
        }
      }
      if (hh == 0){
        #pragma unroll
        for (int ct = 0; ct < 4; ct++){
          acc[0][ct] = __builtin_amdgcn_mfma_f32_16x16x32_bf16(X0, Bs[ct][0], acc[0][ct], 0, 0, 0);
          acc[0][ct] = __builtin_amdgcn_mfma_f32_16x16x32_bf16(X1, Bs[ct][1], acc[0][ct], 0, 0, 0);
        }
      } else {
        #pragma unroll
        for (int ct = 0; ct < 4; ct++){
          acc[1][ct] = __builtin_amdgcn_mfma_f32_16x16x32_bf16(X0, Bs[ct][0], acc[1][ct], 0, 0, 0);
          acc[1][ct] = __builtin_amdgcn_mfma_f32_16x16x32_bf16(X1, Bs[ct][1], acc[1][ct], 0, 0, 0);
        }
      }
    }
  }

  #pragma unroll
  for (int rt = 0; rt < 2; rt++)
    #pragma unroll
    for (int r = 0; r < 4; r++){
      int row = t32*32 + rt*16 + lg*4 + r;
      #pragma unroll
      for (int ct = 0; ct < 4; ct++)
        out[row*CH + ct*16 + li] = acc[rt][ct][r];
    }

  float s1[4], s2[4];
  #pragma unroll
  for (int ct = 0; ct < 4; ct++){
    float a1 = 0.f, a2 = 0.f;
    #pragma unroll
    for (int rt = 0; rt < 2; rt++)
      #pragma unroll
      for (int r = 0; r < 4; r++){
        float v = acc[rt][ct][r];
        a1 += v; a2 += v*v;
      }
    a1 += __shfl_xor(a1, 16, 64); a1 += __shfl_xor(a1, 32, 64);
    a2 += __shfl_xor(a2, 16, 64); a2 += __shfl_xor(a2, 32, 64);
    s1[ct] = a1; s2[ct] = a2;
  }
  __syncthreads();
  if (l < 16){
    #pragma unroll
    for (int ct = 0; ct < 4; ct++){
      sred[wv][0][ct*16 + li] = s1[ct];
      sred[wv][1][ct*16 + li] = s2[ct];
    }
  }
  __syncthreads();
  if (tid < 128){
    int h = tid >> 6, c = tid & 63;
    float p = sred[0][h][c] + sred[1][h][c] + sred[2][h][c] + sred[3][h][c];
    partials[blockIdx.x*128 + tid] = p;
  }
}

// ---- parallel final stats reduce ----
__global__ void k_statred(const float* __restrict__ partials, float* __restrict__ stats){
  __shared__ float sm_[256];
  int c = blockIdx.x;
  int t = threadIdx.x;
  float s = 0.f;
  for (int b = t; b < NBLK2; b += 256) s += partials[b*128 + c];
  sm_[t] = s;
  __syncthreads();
  for (int d = 128; d > 0; d >>= 1){
    if (t < d) sm_[t] += sm_[t+d];
    __syncthreads();
  }
  if (t == 0) stats[c] = sm_[0];
}

// ---- BN (batch stats, biased var) + ReLU, in place ----
__global__ void k_bn(float* __restrict__ out, const float* __restrict__ stats,
                     const float* __restrict__ g, const float* __restrict__ b){
  int i = blockIdx.x * blockDim.x + threadIdx.x;
  float4 v = ((const float4*)out)[i];
  int c0 = (i * 4) & 63;
  float vals[4] = {v.x, v.y, v.z, v.w};
  float res[4];
  #pragma unroll
  for (int q = 0; q < 4; q++){
    int c = c0 + q;
    float mean = stats[c] * (1.0f/NPTS);
    float var  = stats[64+c] * (1.0f/NPTS) - mean*mean;
    float inv  = rsqrtf(var + 1e-5f);
    float y = (vals[q] - mean) * inv * g[c] + b[c];
    res[q] = fmaxf(y, 0.0f);
  }
  float4 r; r.x=res[0]; r.y=res[1]; r.z=res[2]; r.w=res[3];
  ((float4*)out)[i] = r;
}

extern "C" void kernel_launch(void* const* d_in, const int* in_sizes, int n_in,
                              void* d_out, int out_size, void* d_ws, size_t ws_size,
                              hipStream_t stream) {
  const float* feat   = (const float*)d_in[0];
  const int*   kmap   = (const int*)d_in[3];
  const float* weight = (const float*)d_in[4];
  const float* bnw    = (const float*)d_in[5];
  const float* bnb    = (const float*)d_in[6];
  float* out = (float*)d_out;

  char* ws = (char*)d_ws;
  size_t cur = 0;
  auto take = [&](size_t bytes){
    cur = (cur + 255) & ~(size_t)255;
    size_t p = cur; cur += bytes; return p;
  };
  float* stats          = (float*)(ws + take(2*CH*sizeof(float)));
  float* partials       = (float*)(ws + take((size_t)NBLK2*128*sizeof(float)));
  int* cnt              = (int*)(ws + take((size_t)(NSEG+64)*4));   // + spillcnt at [NSEG]
  int2* spill           = (int2*)(ws + take((size_t)SPILLMAX*8));
  unsigned short* wpack = (unsigned short*)(ws + take((size_t)KVOL*CH*CH*2));
  size_t base = cur;
  size_t featb_bytes = (size_t)NPTS*CH*2;
  int C = 16;
  bool useBf16 = false;
  {
    size_t avail = (ws_size > base + featb_bytes + 512) ? (ws_size - base - featb_bytes - 512) : 0;
    size_t cmax = avail / ((size_t)NSEG*4);
    if (cmax >= 11){ useBf16 = true; C = (int)((cmax < 16) ? cmax : 16); }
  }
  bool sorted = useBf16 && (C == 16);
  int* records          = (int*)(ws + take((size_t)NSEG*(useBf16 ? C : 16)*4));
  if (!useBf16) C = 16;
  unsigned short* featb = (unsigned short*)(ws + take(featb_bytes));
  int* spillcnt = cnt + NSEG;

  hipMemsetAsync(cnt, 0, (size_t)(NSEG+64)*4, stream);

  const int2* km = (const int2*)kmap;
  if (useBf16)
    k_pre2<true><<<NPTS*CH/4/256, 256, 0, stream>>>(feat, weight, km, featb, wpack, cnt,
                                                    records, spill, spillcnt, C);
  else
    k_pre2<false><<<TP/256, 256, 0, stream>>>(feat, weight, km, featb, wpack, cnt,
                                              records, spill, spillcnt, C);

  if (sorted){
    k_sort<<<NSEG/32, 256, 0, stream>>>(cnt, records, spill, spillcnt);
    k_conv14<<<NBLK2, 256, 0, stream>>>(featb, wpack, records, spill, spillcnt, out, partials);
  } else if (useBf16){
    k_conv13<true><<<NBLK2, 256, 0, stream>>>(featb, feat, wpack, records, cnt, spill,
                                              spillcnt, C, out, partials);
  } else {
    k_conv13<false><<<NBLK2, 256, 0, stream>>>(featb, feat, wpack, records, cnt, spill,
                                               spillcnt, C, out, partials);
  }

  k_statred<<<128, 256, 0, stream>>>(partials, stats);
  k_bn<<<NPTS*CH/4/256, 256, 0, stream>>>(out, stats, bnw, bnb);
}